// Round 2
// 482.110 us; speedup vs baseline: 1.1220x; 1.1220x over previous
//
#include <hip/hip_runtime.h>

// LieTransport semi-Lagrangian advection, v2b (compile fix of v2).
// B=4, C=64, H=128, W=128, R=16, fp32. Per pixel: bilinear gather of 4
// neighbor R-rows (64 B each), blended with per-pixel weights, over all C.
//
// Changes vs v1 (240 us/dispatch, 2.97 TB/s, occ 29%, FETCH 430 MB vs 268 ideal):
//  1. Split the C loop across blocks (CH=2 per block): grid 1024 -> 32768
//     blocks. v1's grid gave only 4096 waves for 8192 slots (occupancy hard-
//     capped at 50%, measured 29%) -> latency-bound on the random gather.
//  2. XCD-plane blocking: flow is i.i.d. random per pixel, so the gather
//     footprint of one (b,c) plane is the entire 1 MB plane. Swizzle blockIdx
//     so all 256 tiles of a (b, 2-channel) plane-group dispatch consecutively
//     onto the SAME XCD (round-robin blockIdx%8 -> XCD): the 2 MB group
//     working set stays resident in that XCD's 4 MB L2, so each input byte is
//     fetched from HBM once (v1 spread every plane over all 8 XCDs' L2s and
//     re-fetched 1.6x).
//  3. Nontemporal stores (via native ext_vector_type — HIP float4 is a class
//     type the builtin rejects): output is write-once; don't let it evict the
//     gather working set from L2.

constexpr int B = 4, C = 64, H = 128, W = 128, R = 16;
constexpr int CH   = 2;                    // channels per block
constexpr int NXCD = 8;
constexpr int PPB  = 64;                   // pixels per block (256 thr / 4 lanes-per-pixel)
constexpr int TILES  = (H * W) / PPB;      // 256 tiles per plane-group
constexpr int GROUPS = (B * C) / CH;       // 128 plane-groups

typedef float nfloat4 __attribute__((ext_vector_type(4)));

__global__ __launch_bounds__(256) void lie_transport_kernel(
    const float* __restrict__ h_prev,
    const float* __restrict__ flow,
    const float* __restrict__ dt,
    float* __restrict__ out) {
  // ---- block swizzle: physical block -> (xcd, group-on-xcd, tile) ----
  const int blk  = blockIdx.x;
  const int xcd  = blk & (NXCD - 1);        // hw round-robin target XCD
  const int seq  = blk >> 3;                // dispatch order within this XCD
  const int gidx = seq >> 8;                // seq / TILES : 0..15
  const int tile = seq & (TILES - 1);       // 0..255
  const int pg   = gidx * NXCD + xcd;       // global plane-group 0..127
  const int b    = pg >> 5;                 // pg / (C/CH)
  const int c0   = (pg & 31) * CH;

  const int t   = threadIdx.x;
  const int r4  = (t & 3) * 4;              // float4 chunk within R
  const int pix = tile * PPB + (t >> 2);    // pixel within the (b,*) plane
  const int x = pix & (W - 1);
  const int y = pix >> 7;

  // ---- per-pixel coordinate math (identical arithmetic to v1) ----
  const float dtb = dt[b];
  const float* fl = flow + (size_t)b * 2 * H * W;
  const float f0 = fl[y * W + x];
  const float f1 = fl[H * W + y * W + x];

  const float bx = -1.0f + 2.0f * (float)x / (float)(W - 1);
  const float by = -1.0f + 2.0f * (float)y / (float)(H - 1);
  const float gx = bx - f0 * dtb;
  const float gy = by - f1 * dtb;
  float ix = ((gx + 1.0f) * (float)W - 1.0f) * 0.5f;
  float iy = ((gy + 1.0f) * (float)H - 1.0f) * 0.5f;
  ix = fminf(fmaxf(ix, 0.0f), (float)(W - 1));
  iy = fminf(fmaxf(iy, 0.0f), (float)(H - 1));

  const float x0f = floorf(ix);
  const float y0f = floorf(iy);
  const float wx = ix - x0f;
  const float wy = iy - y0f;
  const int x0 = min(max((int)x0f, 0), W - 1);
  const int x1 = min(x0 + 1, W - 1);
  const int y0 = min(max((int)y0f, 0), H - 1);
  const int y1 = min(y0 + 1, H - 1);

  const float w00 = (1.0f - wx) * (1.0f - wy);
  const float w01 = wx * (1.0f - wy);
  const float w10 = (1.0f - wx) * wy;
  const float w11 = wx * wy;

  const size_t chwr = (size_t)H * W * R;
  const size_t base = ((size_t)b * C + c0) * chwr;
  const size_t o00 = ((size_t)(y0 * W + x0)) * R + r4;
  const size_t o01 = ((size_t)(y0 * W + x1)) * R + r4;
  const size_t o10 = ((size_t)(y1 * W + x0)) * R + r4;
  const size_t o11 = ((size_t)(y1 * W + x1)) * R + r4;
  const size_t oou = ((size_t)(y  * W + x )) * R + r4;

#pragma unroll
  for (int cc = 0; cc < CH; ++cc) {
    const size_t cb = base + (size_t)cc * chwr;
    const nfloat4 v00 = *(const nfloat4*)(h_prev + cb + o00);
    const nfloat4 v01 = *(const nfloat4*)(h_prev + cb + o01);
    const nfloat4 v10 = *(const nfloat4*)(h_prev + cb + o10);
    const nfloat4 v11 = *(const nfloat4*)(h_prev + cb + o11);
    nfloat4 r = v00 * w00 + v01 * w01 + v10 * w10 + v11 * w11;
    __builtin_nontemporal_store(r, (nfloat4*)(out + cb + oou));
  }
}

extern "C" void kernel_launch(void* const* d_in, const int* in_sizes, int n_in,
                              void* d_out, int out_size, void* d_ws, size_t ws_size,
                              hipStream_t stream) {
  const float* h_prev = (const float*)d_in[0];
  const float* flow   = (const float*)d_in[1];
  const float* dt     = (const float*)d_in[2];
  float* outp = (float*)d_out;

  const int grid = GROUPS * TILES;   // 32768 blocks, 256 threads each
  lie_transport_kernel<<<grid, 256, 0, stream>>>(h_prev, flow, dt, outp);
}